// Round 5
// baseline (100.107 us; speedup 1.0000x reference)
//
#include <hip/hip_runtime.h>

// Problem constants (from reference setup_inputs): v, v_pred are [4, 8192, 3] fp32.
#define BB 4
#define NN 8192
#define MM 8192
#define BN (BB * NN)

#define BLK 256      // threads per block
#define P   8        // query points per thread
#define NX  (BLK*P)  // 2048 query points per block
#define S   32       // y-chunks -> grid (4,32,4) = 512 blocks, 8 waves/CU
#define MC  (MM/S)   // 256 target points per chunk (4 KB LDS SoA)
#define NBLK_TOTAL ((NN/NX)*S*BB)   // 512

// Key encoding: key = KEY_C - d2. For d2 in [~0, KEY_C) keys are positive
// floats, whose int-punned ordering matches float ordering, so atomicMax(int)
// selects the SMALLEST d2. The harness's 0xAA ws poison (0xAAAAAAAA = negative
// int) loses to any real key — no init kernel needed. True d2 here ~0.02.
// Precision cost of the bias: 128*2^-24 ~ 1.5e-5 << 4.6e-4 threshold.
#define KEY_C 128.0f

// Ticket for last-block-done: ws word starts at the documented poison value.
#define TICKET_POISON 0xAAAAAAAAu

typedef float v2f __attribute__((ext_vector_type(2)));

#if defined(__has_builtin) && __has_builtin(__builtin_elementwise_fma)
#define VFMA(a, b, c) __builtin_elementwise_fma((a), (b), (c))
#else
static __device__ inline v2f VFMA(v2f a, v2f b, v2f c) {
    v2f r; r.x = __builtin_fmaf(a.x, b.x, c.x); r.y = __builtin_fmaf(a.y, b.y, c.y);
    return r;
}
#endif

// Single fused kernel:
//  phase 1: per (x-chunk, y-chunk, batch) block, min_{j in chunk} d2 per query
//           point; atomicMax int-punned key into gkey. Inner loop processes
//           4 y-points per iter: 6 v_pk_fma_f32 + 2 v_min3_f32 per thread
//           per 4 pairs = 2 instr/pair.
//  phase 2: last block to finish (ticket) sums all keys -> mean -> out[0].
__global__ __launch_bounds__(BLK) void chamfer_fused(
    const float* __restrict__ y,    // v      [B, M, 3]  (targets)
    const float* __restrict__ x,    // v_pred [B, N, 3]  (queries)
    int* __restrict__ gkey,         // [B*N] int-punned keys (ws, poisoned)
    unsigned* __restrict__ ticket,  // 1 word (ws, poisoned to 0xAAAAAAAA)
    float* __restrict__ out)        // scalar result
{
    __shared__ __attribute__((aligned(16))) float ZX[MC];
    __shared__ __attribute__((aligned(16))) float ZY[MC];
    __shared__ __attribute__((aligned(16))) float ZZ[MC];
    __shared__ __attribute__((aligned(16))) float ZW[MC];

    const int t  = threadIdx.x;
    const int ib = blockIdx.x;   // x-chunk 0..NN/NX-1
    const int s  = blockIdx.y;   // y-chunk 0..S-1
    const int b  = blockIdx.z;   // batch

    // Stage y chunk into LDS (SoA). MC == BLK: one point/thread, stride-1.
    const float* yb = y + ((size_t)b * MM + (size_t)s * MC) * 3;
    {
        float y0 = yb[3*t + 0];
        float y1 = yb[3*t + 1];
        float y2 = yb[3*t + 2];
        ZX[t] = 2.0f * y0;
        ZY[t] = 2.0f * y1;
        ZZ[t] = 2.0f * y2;
        ZW[t] = __builtin_fmaf(y2, y2, __builtin_fmaf(y1, y1, y0*y0));
    }
    __syncthreads();

    // Load P query points per thread; negate so fma(-x, 2y, acc) works.
    float nx0[P], nx1[P], nx2[P], xx[P], best[P];
    const float* xb = x + ((size_t)b * NN + (size_t)ib * NX) * 3;
#pragma unroll
    for (int p = 0; p < P; ++p) {
        int i = t + p * BLK;
        float a0 = xb[3*i + 0];
        float a1 = xb[3*i + 1];
        float a2 = xb[3*i + 2];
        nx0[p] = -a0; nx1[p] = -a1; nx2[p] = -a2;
        xx[p] = __builtin_fmaf(a2, a2, __builtin_fmaf(a1, a1, a0*a0));
        best[p] = 3.4e38f;
    }

    // Hot loop: per 4 j's, 4 uniform ds_read_b128 (broadcast, conflict-free)
    // + P*(6 pk_fma + 2 min3).
#pragma unroll 2
    for (int jj = 0; jj < MC; jj += 4) {
        float4 ax = ((const float4*)ZX)[jj >> 2];
        float4 ay = ((const float4*)ZY)[jj >> 2];
        float4 az = ((const float4*)ZZ)[jj >> 2];
        float4 aw = ((const float4*)ZW)[jj >> 2];
        v2f zx01 = {ax.x, ax.y}, zx23 = {ax.z, ax.w};
        v2f zy01 = {ay.x, ay.y}, zy23 = {ay.z, ay.w};
        v2f zz01 = {az.x, az.y}, zz23 = {az.z, az.w};
        v2f zw01 = {aw.x, aw.y}, zw23 = {aw.z, aw.w};
#pragma unroll
        for (int p = 0; p < P; ++p) {
            v2f s0 = {nx0[p], nx0[p]};
            v2f s1 = {nx1[p], nx1[p]};
            v2f s2 = {nx2[p], nx2[p]};
            v2f t01 = VFMA(s0, zx01, zw01);
            t01 = VFMA(s1, zy01, t01);
            t01 = VFMA(s2, zz01, t01);
            v2f t23 = VFMA(s0, zx23, zw23);
            t23 = VFMA(s1, zy23, t23);
            t23 = VFMA(s2, zz23, t23);
            // two v_min3_f32: fold 4 candidates + running best
            float m3 = fminf(fminf(t01.x, t01.y), t23.x);
            best[p] = fminf(fminf(m3, t23.y), best[p]);
        }
    }

    // Epilogue: key = KEY_C - (best + xx); atomicMax(int) == float min of d2.
    int* gk = gkey + (size_t)b * NN + (size_t)ib * NX;
#pragma unroll
    for (int p = 0; p < P; ++p) {
        float d2  = best[p] + xx[p];
        float key = KEY_C - d2;
        atomicMax(&gk[t + p * BLK], __float_as_int(key));
    }

    // Last-block-done: device fence, then ticket. Poisoned ticket starts at
    // 0xAAAAAAAA, so the 512th adder sees POISON + 511.
    __threadfence();
    __syncthreads();
    __shared__ int last;
    if (t == 0) {
        unsigned old = atomicAdd(ticket, 1u);
        last = (old == TICKET_POISON + (unsigned)(NBLK_TOTAL - 1));
    }
    __syncthreads();
    if (!last) return;

    // Final reduction by the last block: sum d2 = KEY_C - key over B*N points.
    // gkey lines were only ever touched by device-scope atomics (coherence
    // point); this CU never cached them, so plain loads read fresh data.
    __threadfence();
    const int4* g4 = (const int4*)gkey;
    float acc = 0.0f;
#pragma unroll 4
    for (int i = t; i < BN / 4; i += BLK) {
        int4 k = g4[i];
        acc += (KEY_C - __int_as_float(k.x)) + (KEY_C - __int_as_float(k.y))
             + (KEY_C - __int_as_float(k.z)) + (KEY_C - __int_as_float(k.w));
    }
    for (int off = 32; off > 0; off >>= 1) {
        acc += __shfl_down(acc, off, 64);
    }
    __shared__ float wsum[BLK / 64];
    if ((t & 63) == 0) wsum[t >> 6] = acc;
    __syncthreads();
    if (t == 0) {
        float tot = 0.0f;
#pragma unroll
        for (int i = 0; i < BLK / 64; ++i) tot += wsum[i];
        out[0] = tot * (1.0f / (float)BN);
    }
}

extern "C" void kernel_launch(void* const* d_in, const int* in_sizes, int n_in,
                              void* d_out, int out_size, void* d_ws, size_t ws_size,
                              hipStream_t stream) {
    // setup_inputs order: d_in[0] = v (targets y), d_in[1] = v_pred (queries x)
    const float* v      = (const float*)d_in[0];
    const float* v_pred = (const float*)d_in[1];
    float* out = (float*)d_out;

    int* gkey        = (int*)d_ws;             // [B*N] = 128 KB (poison loses atomicMax)
    unsigned* ticket = (unsigned*)((char*)d_ws + (size_t)BN * sizeof(int));

    dim3 grid1(NN / NX, S, BB);                // (4, 32, 4) = 512 blocks
    chamfer_fused<<<grid1, BLK, 0, stream>>>(v, v_pred, gkey, ticket, out);
}

// Round 6
// 76.621 us; speedup vs baseline: 1.3065x; 1.3065x over previous
//
#include <hip/hip_runtime.h>

// Problem constants (from reference setup_inputs): v, v_pred are [4, 8192, 3] fp32.
#define BB 4
#define NN 8192
#define MM 8192
#define BN (BB * NN)

#define BLK 256      // threads per block
#define P   8        // query points per thread
#define NX  (BLK*P)  // 2048 query points per block
#define S   64       // y-chunks
#define MC  (MM/S)   // 128 target points per chunk (2 KB LDS SoA)
// grid (NN/NX, S, BB) = (4, 64, 4) = 1024 blocks = 4 blocks/CU = 16 waves/CU

// Key encoding: key = KEY_C - d2. For d2 in [~0, KEY_C) keys are positive
// floats, whose int-punned ordering matches float ordering, so atomicMax(int)
// selects the SMALLEST d2. The harness's 0xAA ws poison (0xAAAAAAAA = negative
// int) loses to any real key — no init kernel needed. True d2 here ~0.02.
// Precision cost of the bias: 128*2^-24 ~ 1.5e-5 << 4.6e-4 threshold.
#define KEY_C 128.0f

typedef float v2f __attribute__((ext_vector_type(2)));

#if defined(__has_builtin) && __has_builtin(__builtin_elementwise_fma)
#define VFMA(a, b, c) __builtin_elementwise_fma((a), (b), (c))
#else
static __device__ inline v2f VFMA(v2f a, v2f b, v2f c) {
    v2f r; r.x = __builtin_fmaf(a.x, b.x, c.x); r.y = __builtin_fmaf(a.y, b.y, c.y);
    return r;
}
#endif

// Kernel 1: per (x-chunk ib, y-chunk s, batch b) block, min_{j in chunk} d2
// per query point; atomicMax int-punned key into gkey.
// d2 = xx + (yy - 2 x.y); LDS SoA: (2y0)[j], (2y1)[j], (2y2)[j], (y.y)[j].
// Inner loop, per 4 y-points per thread: 6 v_pk_fma_f32 + 2 v_min3_f32
// = 2 instr/pair. 16 waves/CU hide LDS latency (R5 ran 8 -> 24% VALUBusy).
__global__ __launch_bounds__(BLK) void chamfer_min_atomic(
    const float* __restrict__ y,    // v      [B, M, 3]  (targets)
    const float* __restrict__ x,    // v_pred [B, N, 3]  (queries)
    int* __restrict__ gkey)         // [B*N] int-punned keys (ws, poisoned)
{
    __shared__ __attribute__((aligned(16))) float ZX[MC];
    __shared__ __attribute__((aligned(16))) float ZY[MC];
    __shared__ __attribute__((aligned(16))) float ZZ[MC];
    __shared__ __attribute__((aligned(16))) float ZW[MC];

    const int t  = threadIdx.x;
    const int ib = blockIdx.x;   // x-chunk 0..NN/NX-1
    const int s  = blockIdx.y;   // y-chunk 0..S-1
    const int b  = blockIdx.z;   // batch

    // Stage y chunk into LDS (SoA). MC=128: threads 0..127 stage, stride-1.
    const float* yb = y + ((size_t)b * MM + (size_t)s * MC) * 3;
    if (t < MC) {
        float y0 = yb[3*t + 0];
        float y1 = yb[3*t + 1];
        float y2 = yb[3*t + 2];
        ZX[t] = 2.0f * y0;
        ZY[t] = 2.0f * y1;
        ZZ[t] = 2.0f * y2;
        ZW[t] = __builtin_fmaf(y2, y2, __builtin_fmaf(y1, y1, y0*y0));
    }
    __syncthreads();

    // Load P query points per thread; negate so fma(-x, 2y, acc) works.
    float nx0[P], nx1[P], nx2[P], xx[P], best[P];
    const float* xb = x + ((size_t)b * NN + (size_t)ib * NX) * 3;
#pragma unroll
    for (int p = 0; p < P; ++p) {
        int i = t + p * BLK;
        float a0 = xb[3*i + 0];
        float a1 = xb[3*i + 1];
        float a2 = xb[3*i + 2];
        nx0[p] = -a0; nx1[p] = -a1; nx2[p] = -a2;
        xx[p] = __builtin_fmaf(a2, a2, __builtin_fmaf(a1, a1, a0*a0));
        best[p] = 3.4e38f;
    }

    // Hot loop: per 4 j's, 4 uniform ds_read_b128 (broadcast, conflict-free)
    // + P*(6 pk_fma + 2 min3).
#pragma unroll 2
    for (int jj = 0; jj < MC; jj += 4) {
        float4 ax = ((const float4*)ZX)[jj >> 2];
        float4 ay = ((const float4*)ZY)[jj >> 2];
        float4 az = ((const float4*)ZZ)[jj >> 2];
        float4 aw = ((const float4*)ZW)[jj >> 2];
        v2f zx01 = {ax.x, ax.y}, zx23 = {ax.z, ax.w};
        v2f zy01 = {ay.x, ay.y}, zy23 = {ay.z, ay.w};
        v2f zz01 = {az.x, az.y}, zz23 = {az.z, az.w};
        v2f zw01 = {aw.x, aw.y}, zw23 = {aw.z, aw.w};
#pragma unroll
        for (int p = 0; p < P; ++p) {
            v2f s0 = {nx0[p], nx0[p]};
            v2f s1 = {nx1[p], nx1[p]};
            v2f s2 = {nx2[p], nx2[p]};
            v2f t01 = VFMA(s0, zx01, zw01);
            t01 = VFMA(s1, zy01, t01);
            t01 = VFMA(s2, zz01, t01);
            v2f t23 = VFMA(s0, zx23, zw23);
            t23 = VFMA(s1, zy23, t23);
            t23 = VFMA(s2, zz23, t23);
            // two v_min3_f32: fold 4 candidates + running best
            float m3 = fminf(fminf(t01.x, t01.y), t23.x);
            best[p] = fminf(fminf(m3, t23.y), best[p]);
        }
    }

    // Epilogue: key = KEY_C - (best + xx); atomicMax(int) == float min of d2.
    int* gk = gkey + (size_t)b * NN + (size_t)ib * NX;
#pragma unroll
    for (int p = 0; p < P; ++p) {
        float d2  = best[p] + xx[p];
        float key = KEY_C - d2;
        atomicMax(&gk[t + p * BLK], __float_as_int(key));
    }
}

// Kernel 2: single block, sum d2 = KEY_C - key over all B*N points -> mean.
__global__ __launch_bounds__(1024) void final_sum(
    const int* __restrict__ gkey,   // [B*N]
    float* __restrict__ out)
{
    const int t = threadIdx.x;  // 1024 threads = 16 waves
    const int4* g4 = (const int4*)gkey;
    float acc = 0.0f;
#pragma unroll
    for (int i = t; i < BN / 4; i += 1024) {
        int4 k = g4[i];
        acc += (KEY_C - __int_as_float(k.x)) + (KEY_C - __int_as_float(k.y))
             + (KEY_C - __int_as_float(k.z)) + (KEY_C - __int_as_float(k.w));
    }
    // wave-64 sum reduce
    for (int off = 32; off > 0; off >>= 1) {
        acc += __shfl_down(acc, off, 64);
    }
    __shared__ float wsum[16];
    const int lane = t & 63;
    const int w    = t >> 6;
    if (lane == 0) wsum[w] = acc;
    __syncthreads();
    if (t == 0) {
        float tot = 0.0f;
#pragma unroll
        for (int i = 0; i < 16; ++i) tot += wsum[i];
        out[0] = tot * (1.0f / (float)BN);
    }
}

extern "C" void kernel_launch(void* const* d_in, const int* in_sizes, int n_in,
                              void* d_out, int out_size, void* d_ws, size_t ws_size,
                              hipStream_t stream) {
    // setup_inputs order: d_in[0] = v (targets y), d_in[1] = v_pred (queries x)
    const float* v      = (const float*)d_in[0];
    const float* v_pred = (const float*)d_in[1];
    float* out = (float*)d_out;

    int* gkey = (int*)d_ws;                  // [B*N] = 128 KB (poison loses atomicMax)

    dim3 grid1(NN / NX, S, BB);              // (4, 64, 4) = 1024 blocks
    chamfer_min_atomic<<<grid1, BLK, 0, stream>>>(v, v_pred, gkey);

    final_sum<<<1, 1024, 0, stream>>>(gkey, out);
}